// Round 2
// baseline (318.578 us; speedup 1.0000x reference)
//
#include <hip/hip_runtime.h>

#define EMBED 1024
#define SEQL  2048
#define NHEAD 16
#define HDIM  64
#define NBATCH 2
#define MROWS 4096   // NBATCH*SEQL

typedef __attribute__((ext_vector_type(4))) float  f32x4;
typedef __attribute__((ext_vector_type(8))) __bf16 bf16x8;

__device__ __forceinline__ short f2bf(float f){
  union { float f; unsigned u; } x; x.f = f;
  unsigned r = x.u + 0x7fffu + ((x.u >> 16) & 1u);
  return (short)(r >> 16);
}

#define GLDS(gp, lp) __builtin_amdgcn_global_load_lds( \
    (const __attribute__((address_space(1))) void*)(gp), \
    (__attribute__((address_space(3))) void*)(lp), 16, 0, 0)

// ---------------- fp32 -> bf16 convert (x) ----------------
__global__ __launch_bounds__(256) void cvt_kernel(const float* __restrict__ in,
                                                  short* __restrict__ out, int n){
  int i = (blockIdx.x * 256 + threadIdx.x) * 4;
  if (i >= n) return;
  float4 v = *(const float4*)(in + i);
  short4 o; o.x = f2bf(v.x); o.y = f2bf(v.y); o.z = f2bf(v.z); o.w = f2bf(v.w);
  *(short4*)(out + i) = o;
}

// ------- W [K][N] fp32 -> Wt [N][K] bf16, 4 matrices via blockIdx.z -------
__global__ __launch_bounds__(256) void transpose_kernel(const float* __restrict__ W0,
    const float* __restrict__ W1, const float* __restrict__ W2, const float* __restrict__ W3,
    short* __restrict__ WtAll){
  __shared__ float tile[32][33];
  const int z = blockIdx.z;
  const float* W = (z==0)?W0:(z==1)?W1:(z==2)?W2:W3;
  short* Wt = WtAll + z*(EMBED*EMBED);
  const int bx = blockIdx.x*32, by = blockIdx.y*32;
  const int tx = threadIdx.x & 31, ty = threadIdx.x >> 5;
  #pragma unroll
  for (int i=0;i<32;i+=8) tile[ty+i][tx] = W[(by+ty+i)*EMBED + bx+tx];
  __syncthreads();
  #pragma unroll
  for (int i=0;i<32;i+=8) Wt[(bx+ty+i)*EMBED + by+tx] = f2bf(tile[tx][ty+i]);
}

// ---------------- 128x128 bf16 GEMM mainloop (m97 structure) ----------------
__device__ __forceinline__ void gemm_tile_128(const short* __restrict__ A,
    const short* __restrict__ Bt, short* As, short* Bs, int m0, int n0, f32x4 acc[4][4]){
  const int tid  = threadIdx.x;
  const int lane = tid & 63;
  const int wid  = tid >> 6;
  const int wrow = (wid >> 1) * 64, wcol = (wid & 1) * 64;
  const int arow = tid >> 2, acol8 = (tid & 3) * 8;
  const int l15 = lane & 15, lg = lane >> 4;
  for (int k0 = 0; k0 < 1024; k0 += 32){
    __syncthreads();
    GLDS(A  + (m0      + arow) * 1024 + k0 + acol8, As + tid*8);
    GLDS(A  + (m0 + 64 + arow) * 1024 + k0 + acol8, As + 2048 + tid*8);
    GLDS(Bt + (n0      + arow) * 1024 + k0 + acol8, Bs + tid*8);
    GLDS(Bt + (n0 + 64 + arow) * 1024 + k0 + acol8, Bs + 2048 + tid*8);
    __syncthreads();
    bf16x8 a[4], b[4];
    #pragma unroll
    for (int i=0;i<4;++i) a[i] = *(const bf16x8*)(As + (wrow+16*i+l15)*32 + 8*lg);
    #pragma unroll
    for (int j=0;j<4;++j) b[j] = *(const bf16x8*)(Bs + (wcol+16*j+l15)*32 + 8*lg);
    #pragma unroll
    for (int i=0;i<4;++i)
      #pragma unroll
      for (int j=0;j<4;++j)
        acc[i][j] = __builtin_amdgcn_mfma_f32_16x16x32_bf16(a[i], b[j], acc[i][j], 0,0,0);
  }
}

// QKV projections: z=0 -> Q [b,h,s,d] (pre-scaled), z=1 -> K, z=2 -> V^T [b,h,d,s]
__global__ __launch_bounds__(256) void gemm_qkv_kernel(const short* __restrict__ Xb,
    const short* __restrict__ WtAll, short* __restrict__ Q, short* __restrict__ K,
    short* __restrict__ Vt){
  __shared__ short As[4096], Bs[4096];
  const int m0 = blockIdx.x*128, n0 = blockIdx.y*128, z = blockIdx.z;
  const short* Bt = WtAll + z*(EMBED*EMBED);
  f32x4 acc[4][4] = {};
  gemm_tile_128(Xb, Bt, As, Bs, m0, n0, acc);
  const int lane = threadIdx.x & 63;
  const int wid  = threadIdx.x >> 6;
  const int wrow = (wid >> 1) * 64, wcol = (wid & 1) * 64;
  const int l15 = lane & 15, lg = lane >> 4;
  short* out = (z==0) ? Q : (z==1) ? K : Vt;
  // fold softmax scale (1/8) and log2(e) into Q
  const float qscl = (z==0) ? (0.125f * 1.44269504f) : 1.0f;
  #pragma unroll
  for (int i=0;i<4;++i)
    #pragma unroll
    for (int j=0;j<4;++j)
      #pragma unroll
      for (int r=0;r<4;++r){
        int m = m0 + wrow + 16*i + 4*lg + r;
        int n = n0 + wcol + 16*j + l15;
        int bb = m >> 11, srow = m & 2047, hh = n >> 6, d = n & 63;
        short v = f2bf(acc[i][j][r] * qscl);
        if (z < 2) out[(((bb<<4)+hh)*SEQL + srow)*HDIM + d] = v;
        else       out[(((bb<<4)+hh)*HDIM + d)*SEQL + srow] = v;
      }
}

// Output projection: out = Ctx @ W_o + b_o (fp32)
__global__ __launch_bounds__(256) void gemm_out_kernel(const short* __restrict__ Ctx,
    const short* __restrict__ WtO, const float* __restrict__ bias, float* __restrict__ out){
  __shared__ short As[4096], Bs[4096];
  const int m0 = blockIdx.x*128, n0 = blockIdx.y*128;
  f32x4 acc[4][4] = {};
  gemm_tile_128(Ctx, WtO, As, Bs, m0, n0, acc);
  const int lane = threadIdx.x & 63;
  const int wid  = threadIdx.x >> 6;
  const int wrow = (wid >> 1) * 64, wcol = (wid & 1) * 64;
  const int l15 = lane & 15, lg = lane >> 4;
  #pragma unroll
  for (int i=0;i<4;++i)
    #pragma unroll
    for (int j=0;j<4;++j)
      #pragma unroll
      for (int r=0;r<4;++r){
        int m = m0 + wrow + 16*i + 4*lg + r;
        int n = n0 + wcol + 16*j + l15;
        out[m*EMBED + n] = acc[i][j][r] + bias[n];
      }
}

// ---------------- causal flash attention v2 ----------------
// grid (64, B*H), 2 waves/block, 16 q-rows/wave, KV tile = 64.
// Heavy-first dispatch (bx reversed); K[t+1] + V[t] register prefetch.
// Q was pre-scaled by 0.125*log2(e); softmax in exp2 space.

#define ATTN_STEP(KCUR, KNXT) do {                                            \
    const int kv0 = t*64;                                                     \
    /* S = Q K^T (16 q x 64 kv), exp2 domain */                               \
    f32x4 sc[4];                                                              \
    _Pragma("unroll")                                                         \
    for (int c=0;c<4;++c){                                                    \
      f32x4 z = (f32x4){0.f,0.f,0.f,0.f};                                     \
      z = __builtin_amdgcn_mfma_f32_16x16x32_bf16(aq0, KCUR[c][0], z, 0,0,0); \
      z = __builtin_amdgcn_mfma_f32_16x16x32_bf16(aq1, KCUR[c][1], z, 0,0,0); \
      sc[c] = z;                                                              \
    }                                                                         \
    /* prefetch V[t] and K[t+1] so L2 latency hides under softmax */          \
    bf16x8 vr[4][2];                                                          \
    _Pragma("unroll")                                                         \
    for (int j=0;j<4;++j){                                                    \
      const short* vp = Vh + (16*j + l15)*SEQL + kv0 + 8*lg;                  \
      vr[j][0] = *(const bf16x8*)vp;                                          \
      vr[j][1] = *(const bf16x8*)(vp + 32);                                   \
    }                                                                         \
    if (t + 1 < nt){                                                          \
      _Pragma("unroll")                                                       \
      for (int c=0;c<4;++c){                                                  \
        const short* kp = Kh + (kv0 + 64 + 16*c + l15)*HDIM + 8*lg;           \
        KNXT[c][0] = *(const bf16x8*)kp;                                      \
        KNXT[c][1] = *(const bf16x8*)(kp + 32);                               \
      }                                                                       \
    }                                                                         \
    /* mask + row max (D layout: row q = 4*lg + r, col kv = 16c + l15) */     \
    const bool last = (t == nt - 1);                                          \
    float pm[4] = {-3e30f,-3e30f,-3e30f,-3e30f};                              \
    _Pragma("unroll")                                                         \
    for (int c=0;c<4;++c)                                                     \
      _Pragma("unroll")                                                       \
      for (int r=0;r<4;++r){                                                  \
        float v = sc[c][r];                                                   \
        if (last && (kv0 + 16*c + l15 > q0w + 4*lg + r)) v = -3e30f;          \
        sc[c][r] = v;                                                         \
        pm[r] = fmaxf(pm[r], v);                                              \
      }                                                                       \
    _Pragma("unroll")                                                         \
    for (int r=0;r<4;++r){                                                    \
      float mx = pm[r];                                                       \
      mx = fmaxf(mx, __shfl_xor(mx, 1));                                      \
      mx = fmaxf(mx, __shfl_xor(mx, 2));                                      \
      mx = fmaxf(mx, __shfl_xor(mx, 4));                                      \
      mx = fmaxf(mx, __shfl_xor(mx, 8));                                      \
      float mn = fmaxf(mrun[r], mx);                                          \
      float sscale = __builtin_amdgcn_exp2f(mrun[r] - mn);                    \
      mrun[r] = mn;                                                           \
      float lsum = 0.f;                                                       \
      _Pragma("unroll")                                                       \
      for (int c=0;c<4;++c){                                                  \
        float p = __builtin_amdgcn_exp2f(sc[c][r] - mn);                      \
        sc[c][r] = p;                                                         \
        lsum += p;                                                            \
      }                                                                       \
      lsum += __shfl_xor(lsum, 1);                                            \
      lsum += __shfl_xor(lsum, 2);                                            \
      lsum += __shfl_xor(lsum, 4);                                            \
      lsum += __shfl_xor(lsum, 8);                                            \
      lrun[r] = lrun[r]*sscale + lsum;                                        \
      _Pragma("unroll")                                                       \
      for (int j=0;j<4;++j) acc[j][r] *= sscale;                              \
    }                                                                         \
    /* P -> per-wave LDS, XOR-swizzled rows */                                \
    _Pragma("unroll")                                                         \
    for (int c=0;c<4;++c)                                                     \
      _Pragma("unroll")                                                       \
      for (int r=0;r<4;++r){                                                  \
        int q = 4*lg + r, kv = 16*c + l15;                                    \
        pw[q*64 + (kv ^ ((q & 7) << 3))] = f2bf(sc[c][r]);                    \
      }                                                                       \
    bf16x8 pa0 = *(const bf16x8*)(pw + l15*64 + ((8*lg)      ^ ((l15 & 7) << 3))); \
    bf16x8 pa1 = *(const bf16x8*)(pw + l15*64 + ((32 + 8*lg) ^ ((l15 & 7) << 3))); \
    _Pragma("unroll")                                                         \
    for (int j=0;j<4;++j){                                                    \
      acc[j] = __builtin_amdgcn_mfma_f32_16x16x32_bf16(pa0, vr[j][0], acc[j], 0,0,0); \
      acc[j] = __builtin_amdgcn_mfma_f32_16x16x32_bf16(pa1, vr[j][1], acc[j], 0,0,0); \
    }                                                                         \
  } while(0)

__global__ __launch_bounds__(128, 3) void attn_kernel(const short* __restrict__ Q,
    const short* __restrict__ K, const short* __restrict__ Vt, short* __restrict__ Ctx){
  __shared__ short Pl[2*16*64];     // per-wave 16x64 bf16 P tile, XOR-swizzled
  const int lane = threadIdx.x & 63;
  const int wid  = threadIdx.x >> 6;
  const int bx = 63 - (int)blockIdx.x;  // heavy-first dispatch
  const int bh = blockIdx.y;            // b*16 + h
  const int q0w = bx*32 + wid*16;       // this wave's first q row
  const short* Qh = Q  + bh*(SEQL*HDIM);
  const short* Kh = K  + bh*(SEQL*HDIM);
  const short* Vh = Vt + bh*(HDIM*SEQL);
  const int l15 = lane & 15, lg = lane >> 4;

  const short* qp = Qh + (q0w + l15)*HDIM + 8*lg;
  bf16x8 aq0 = *(const bf16x8*)qp;
  bf16x8 aq1 = *(const bf16x8*)(qp + 32);

  f32x4 acc[4];
  float mrun[4], lrun[4];
  #pragma unroll
  for (int j=0;j<4;++j) acc[j] = (f32x4){0.f,0.f,0.f,0.f};
  #pragma unroll
  for (int r=0;r<4;++r){ mrun[r] = -3e30f; lrun[r] = 0.f; }

  short* pw = Pl + wid*1024;
  const int nt = (q0w >> 6) + 1;        // causal tile count for this wave

  bf16x8 krA[4][2], krB[4][2];
  #pragma unroll
  for (int c=0;c<4;++c){
    const short* kp = Kh + (16*c + l15)*HDIM + 8*lg;
    krA[c][0] = *(const bf16x8*)kp;
    krA[c][1] = *(const bf16x8*)(kp + 32);
  }

  int t = 0;
  while (true){
    ATTN_STEP(krA, krB);
    if (++t >= nt) break;
    ATTN_STEP(krB, krA);
    if (++t >= nt) break;
  }

  // epilogue: O * (1/l), write ctx [b, s, h*64+d] bf16
  const int bb = bh >> 4, hh = bh & 15;
  float rl[4];
  #pragma unroll
  for (int r=0;r<4;++r) rl[r] = __builtin_amdgcn_rcpf(lrun[r]);
  #pragma unroll
  for (int j=0;j<4;++j)
    #pragma unroll
    for (int r=0;r<4;++r){
      int qg = q0w + 4*lg + r;
      int d  = 16*j + l15;
      Ctx[(bb*SEQL + qg)*EMBED + hh*HDIM + d] = f2bf(acc[j][r] * rl[r]);
    }
}

extern "C" void kernel_launch(void* const* d_in, const int* in_sizes, int n_in,
                              void* d_out, int out_size, void* d_ws, size_t ws_size,
                              hipStream_t stream){
  const float* x  = (const float*)d_in[0];
  const float* Wq = (const float*)d_in[1];
  const float* Wk = (const float*)d_in[2];
  const float* Wv = (const float*)d_in[3];
  const float* Wo = (const float*)d_in[4];
  const float* bo = (const float*)d_in[5];
  float* out = (float*)d_out;

  char* ws = (char*)d_ws;
  const size_t MB = 1u << 20;
  short* Xb  = (short*)(ws +  0*MB);  // [4096][1024] bf16 (8 MB)
  short* Wt  = (short*)(ws +  8*MB);  // 4x [1024][1024] bf16 transposed (8 MB)
  short* Q   = (short*)(ws + 16*MB);  // [b,h,s,d] (8 MB)
  short* Kk  = (short*)(ws + 24*MB);  // [b,h,s,d] (8 MB)
  short* Vt  = (short*)(ws + 32*MB);  // [b,h,d,s] (8 MB)
  short* Ctx = (short*)(ws + 40*MB);  // [b,s,e]   (8 MB)

  cvt_kernel<<<4096, 256, 0, stream>>>(x, Xb, MROWS*EMBED);
  transpose_kernel<<<dim3(32,32,4), 256, 0, stream>>>(Wq, Wk, Wv, Wo, Wt);
  gemm_qkv_kernel<<<dim3(32,8,3), 256, 0, stream>>>(Xb, Wt, Q, Kk, Vt);
  attn_kernel<<<dim3(64,32), 128, 0, stream>>>(Q, Kk, Vt, Ctx);
  gemm_out_kernel<<<dim3(32,8), 256, 0, stream>>>(Ctx, Wt + 3*(EMBED*EMBED), bo, out);
}

// Round 3
// 140.819 us; speedup vs baseline: 2.2623x; 2.2623x over previous
//
#include <hip/hip_runtime.h>

#define EMBED 1024
#define SEQL  2048
#define NHEAD 16
#define HDIM  64
#define NBATCH 2
#define MROWS 4096   // NBATCH*SEQL

typedef __attribute__((ext_vector_type(4))) float  f32x4;
typedef __attribute__((ext_vector_type(8))) __bf16 bf16x8;

__device__ __forceinline__ short f2bf(float f){
  union { float f; unsigned u; } x; x.f = f;
  unsigned r = x.u + 0x7fffu + ((x.u >> 16) & 1u);
  return (short)(r >> 16);
}

#define GLDS(gp, lp) __builtin_amdgcn_global_load_lds( \
    (const __attribute__((address_space(1))) void*)(gp), \
    (__attribute__((address_space(3))) void*)(lp), 16, 0, 0)

// ---------------- fp32 -> bf16 convert (x) ----------------
__global__ __launch_bounds__(256) void cvt_kernel(const float* __restrict__ in,
                                                  short* __restrict__ out, int n){
  int i = (blockIdx.x * 256 + threadIdx.x) * 4;
  if (i >= n) return;
  float4 v = *(const float4*)(in + i);
  short4 o; o.x = f2bf(v.x); o.y = f2bf(v.y); o.z = f2bf(v.z); o.w = f2bf(v.w);
  *(short4*)(out + i) = o;
}

// ------- W [K][N] fp32 -> Wt [N][K] bf16, 4 matrices via blockIdx.z -------
__global__ __launch_bounds__(256) void transpose_kernel(const float* __restrict__ W0,
    const float* __restrict__ W1, const float* __restrict__ W2, const float* __restrict__ W3,
    short* __restrict__ WtAll){
  __shared__ float tile[32][33];
  const int z = blockIdx.z;
  const float* W = (z==0)?W0:(z==1)?W1:(z==2)?W2:W3;
  short* Wt = WtAll + z*(EMBED*EMBED);
  const int bx = blockIdx.x*32, by = blockIdx.y*32;
  const int tx = threadIdx.x & 31, ty = threadIdx.x >> 5;
  #pragma unroll
  for (int i=0;i<32;i+=8) tile[ty+i][tx] = W[(by+ty+i)*EMBED + bx+tx];
  __syncthreads();
  #pragma unroll
  for (int i=0;i<32;i+=8) Wt[(bx+ty+i)*EMBED + by+tx] = f2bf(tile[tx][ty+i]);
}

// ---------------- 128x128 bf16 GEMM mainloop (m97 structure) ----------------
__device__ __forceinline__ void gemm_tile_128(const short* __restrict__ A,
    const short* __restrict__ Bt, short* As, short* Bs, int m0, int n0, f32x4 acc[4][4]){
  const int tid  = threadIdx.x;
  const int lane = tid & 63;
  const int wid  = tid >> 6;
  const int wrow = (wid >> 1) * 64, wcol = (wid & 1) * 64;
  const int arow = tid >> 2, acol8 = (tid & 3) * 8;
  const int l15 = lane & 15, lg = lane >> 4;
  for (int k0 = 0; k0 < 1024; k0 += 32){
    __syncthreads();
    GLDS(A  + (m0      + arow) * 1024 + k0 + acol8, As + tid*8);
    GLDS(A  + (m0 + 64 + arow) * 1024 + k0 + acol8, As + 2048 + tid*8);
    GLDS(Bt + (n0      + arow) * 1024 + k0 + acol8, Bs + tid*8);
    GLDS(Bt + (n0 + 64 + arow) * 1024 + k0 + acol8, Bs + 2048 + tid*8);
    __syncthreads();
    bf16x8 a[4], b[4];
    #pragma unroll
    for (int i=0;i<4;++i) a[i] = *(const bf16x8*)(As + (wrow+16*i+l15)*32 + 8*lg);
    #pragma unroll
    for (int j=0;j<4;++j) b[j] = *(const bf16x8*)(Bs + (wcol+16*j+l15)*32 + 8*lg);
    #pragma unroll
    for (int i=0;i<4;++i)
      #pragma unroll
      for (int j=0;j<4;++j)
        acc[i][j] = __builtin_amdgcn_mfma_f32_16x16x32_bf16(a[i], b[j], acc[i][j], 0,0,0);
  }
}

// QKV projections: z=0 -> Q [b,h,s,d] (pre-scaled), z=1 -> K, z=2 -> V^T [b,h,d,s]
__global__ __launch_bounds__(256) void gemm_qkv_kernel(const short* __restrict__ Xb,
    const short* __restrict__ WtAll, short* __restrict__ Q, short* __restrict__ K,
    short* __restrict__ Vt){
  __shared__ short As[4096], Bs[4096];
  const int m0 = blockIdx.x*128, n0 = blockIdx.y*128, z = blockIdx.z;
  const short* Bt = WtAll + z*(EMBED*EMBED);
  f32x4 acc[4][4] = {};
  gemm_tile_128(Xb, Bt, As, Bs, m0, n0, acc);
  const int lane = threadIdx.x & 63;
  const int wid  = threadIdx.x >> 6;
  const int wrow = (wid >> 1) * 64, wcol = (wid & 1) * 64;
  const int l15 = lane & 15, lg = lane >> 4;
  short* out = (z==0) ? Q : (z==1) ? K : Vt;
  // fold softmax scale (1/8) and log2(e) into Q
  const float qscl = (z==0) ? (0.125f * 1.44269504f) : 1.0f;
  #pragma unroll
  for (int i=0;i<4;++i)
    #pragma unroll
    for (int j=0;j<4;++j)
      #pragma unroll
      for (int r=0;r<4;++r){
        int m = m0 + wrow + 16*i + 4*lg + r;
        int n = n0 + wcol + 16*j + l15;
        int bb = m >> 11, srow = m & 2047, hh = n >> 6, d = n & 63;
        short v = f2bf(acc[i][j][r] * qscl);
        if (z < 2) out[(((bb<<4)+hh)*SEQL + srow)*HDIM + d] = v;
        else       out[(((bb<<4)+hh)*HDIM + d)*SEQL + srow] = v;
      }
}

// Output projection: out = Ctx @ W_o + b_o (fp32)
__global__ __launch_bounds__(256) void gemm_out_kernel(const short* __restrict__ Ctx,
    const short* __restrict__ WtO, const float* __restrict__ bias, float* __restrict__ out){
  __shared__ short As[4096], Bs[4096];
  const int m0 = blockIdx.x*128, n0 = blockIdx.y*128;
  f32x4 acc[4][4] = {};
  gemm_tile_128(Ctx, WtO, As, Bs, m0, n0, acc);
  const int lane = threadIdx.x & 63;
  const int wid  = threadIdx.x >> 6;
  const int wrow = (wid >> 1) * 64, wcol = (wid & 1) * 64;
  const int l15 = lane & 15, lg = lane >> 4;
  #pragma unroll
  for (int i=0;i<4;++i)
    #pragma unroll
    for (int j=0;j<4;++j)
      #pragma unroll
      for (int r=0;r<4;++r){
        int m = m0 + wrow + 16*i + 4*lg + r;
        int n = n0 + wcol + 16*j + l15;
        out[m*EMBED + n] = acc[i][j][r] + bias[n];
      }
}

// ---------------- causal flash attention v3 (swapped QK^T) ----------------
// 1024 blocks x 2 waves. Wave = 32 q rows (2 groups of 16), KV tile = 64.
// Block pairs slice i with 63-i (balanced). Head h clustered on XCD h%8.
// S^T = mfma(K, Q): lane col = q (l15), rows = kv (4*lg+r) -> row-softmax is
// in-lane + 2 shfl_xor. P via per-wave swizzled LDS (short4 writes).
__global__ __launch_bounds__(128, 2) void attn_kernel(const short* __restrict__ Q,
    const short* __restrict__ K, const short* __restrict__ Vt, short* __restrict__ Ctx){
  __shared__ short Pl[2*32*64];     // per-wave 32x64 bf16 P tile, XOR-swizzled
  const int tid  = threadIdx.x;
  const int lane = tid & 63;
  const int wid  = tid >> 6;
  // bid -> (xcd, head, slice): head h lands on XCD h%8 (L2 clustering)
  const int bid    = blockIdx.x;        // 0..1023
  const int xcd    = bid & 7;
  const int i7     = bid >> 3;          // 0..127
  const int bh     = xcd + 8*(i7 >> 5); // head 0..31 (4 heads per XCD)
  const int islice = i7 & 31;           // 0..31
  const int slice  = wid ? (63 - islice) : islice;  // balanced pair per block
  const int q0w    = slice * 32;

  const short* Qh = Q  + bh*(SEQL*HDIM);
  const short* Kh = K  + bh*(SEQL*HDIM);
  const short* Vh = Vt + bh*(HDIM*SEQL);
  const int l15 = lane & 15, lg = lane >> 4;
  const int lg20 = 20 * lg;
  const int sw = (l15 & 7) << 3;        // P swizzle (row & 7) << 3, row = 16g+l15

  // Q fragments (B-operand): lane col = q row (l15), k-chunk over d
  bf16x8 bq[2][2];
  #pragma unroll
  for (int g=0; g<2; ++g){
    const short* qp = Qh + (q0w + 16*g + l15)*HDIM + 8*lg;
    bq[g][0] = *(const bf16x8*)qp;
    bq[g][1] = *(const bf16x8*)(qp + 32);
  }

  f32x4 acc[2][4];                      // [g][j]: rows q=16g+4lg+r, cols d=16j+l15
  float mrun[2], lrun[2];
  #pragma unroll
  for (int g=0; g<2; ++g){
    mrun[g] = -3e30f; lrun[g] = 0.f;
    #pragma unroll
    for (int j=0; j<4; ++j) acc[g][j] = (f32x4){0.f,0.f,0.f,0.f};
  }

  short* pw = Pl + wid*2048;            // per-wave 32x64 bf16
  const int nt = (q0w >> 6) + 1;

  // preload K tile 0 (A-operand: lane row = kv (l15), k-chunk over d)
  bf16x8 kr[4][2];
  #pragma unroll
  for (int c=0; c<4; ++c){
    const short* kp = Kh + (16*c + l15)*HDIM + 8*lg;
    kr[c][0] = *(const bf16x8*)kp;
    kr[c][1] = *(const bf16x8*)(kp + 32);
  }

  for (int t = 0; t < nt; ++t){
    const int kv0 = t*64;
    // S^T = K Q^T: sc[c][g] tile: rows kv=16c+4lg+r, cols q=16g+l15
    f32x4 sc[4][2];
    #pragma unroll
    for (int c=0; c<4; ++c)
      #pragma unroll
      for (int g=0; g<2; ++g){
        f32x4 z = (f32x4){0.f,0.f,0.f,0.f};
        z = __builtin_amdgcn_mfma_f32_16x16x32_bf16(kr[c][0], bq[g][0], z, 0,0,0);
        z = __builtin_amdgcn_mfma_f32_16x16x32_bf16(kr[c][1], bq[g][1], z, 0,0,0);
        sc[c][g] = z;
      }
    // issue V[t] loads (consumed after softmax)
    bf16x8 vr[4][2];
    #pragma unroll
    for (int j=0; j<4; ++j){
      const short* vp = Vh + (16*j + l15)*SEQL + kv0 + 8*lg;
      vr[j][0] = *(const bf16x8*)vp;
      vr[j][1] = *(const bf16x8*)(vp + 32);
    }
    // reload kr with K tile t+1 (WAR on kr regs; latency hides under softmax)
    if (t + 1 < nt){
      #pragma unroll
      for (int c=0; c<4; ++c){
        const short* kp = Kh + (kv0 + 64 + 16*c + l15)*HDIM + 8*lg;
        kr[c][0] = *(const bf16x8*)kp;
        kr[c][1] = *(const bf16x8*)(kp + 32);
      }
    }
    // causal mask (last tile only): kv = kv0+16c+4lg+r vs q = q0w+16g+l15
    if (t == nt - 1){
      #pragma unroll
      for (int c=0; c<4; ++c)
        #pragma unroll
        for (int g=0; g<2; ++g)
          #pragma unroll
          for (int r=0; r<4; ++r)
            if (kv0 + 16*c + 4*lg + r > q0w + 16*g + l15) sc[c][g][r] = -3e30f;
    }
    // online softmax per q-group: in-lane over 16 values + 2 shuffles
    float srg[2][4];
    #pragma unroll
    for (int g=0; g<2; ++g){
      float pm = -3e30f;
      #pragma unroll
      for (int c=0; c<4; ++c)
        #pragma unroll
        for (int r=0; r<4; ++r) pm = fmaxf(pm, sc[c][g][r]);
      pm = fmaxf(pm, __shfl_xor(pm, 16));
      pm = fmaxf(pm, __shfl_xor(pm, 32));
      float mn = fmaxf(mrun[g], pm);
      float ss = __builtin_amdgcn_exp2f(mrun[g] - mn);
      mrun[g] = mn;
      float ls = 0.f;
      #pragma unroll
      for (int c=0; c<4; ++c)
        #pragma unroll
        for (int r=0; r<4; ++r){
          float p = __builtin_amdgcn_exp2f(sc[c][g][r] - mn);
          sc[c][g][r] = p;
          ls += p;
        }
      ls += __shfl_xor(ls, 16);
      ls += __shfl_xor(ls, 32);
      lrun[g] = lrun[g]*ss + ls;
      // redistribute sscale from q=l15 lanes to acc rows q=4lg+r
      #pragma unroll
      for (int r=0; r<4; ++r) srg[g][r] = __shfl(ss, lg20 + r);
    }
    #pragma unroll
    for (int g=0; g<2; ++g)
      #pragma unroll
      for (int j=0; j<4; ++j)
        #pragma unroll
        for (int r=0; r<4; ++r) acc[g][j][r] *= srg[g][r];
    // P -> LDS: lane holds kv=16c+4lg..+3 (contiguous) for row q=16g+l15
    #pragma unroll
    for (int g=0; g<2; ++g)
      #pragma unroll
      for (int c=0; c<4; ++c){
        short4 pk;
        pk.x = f2bf(sc[c][g][0]); pk.y = f2bf(sc[c][g][1]);
        pk.z = f2bf(sc[c][g][2]); pk.w = f2bf(sc[c][g][3]);
        *(short4*)(pw + (16*g + l15)*64 + ((16*c + 4*lg) ^ sw)) = pk;
      }
    // P read as PV A-frags: row q=16g+l15, k-chunk 8lg within 32m
    bf16x8 pa[2][2];
    #pragma unroll
    for (int g=0; g<2; ++g)
      #pragma unroll
      for (int m=0; m<2; ++m)
        pa[g][m] = *(const bf16x8*)(pw + (16*g + l15)*64 + ((32*m + 8*lg) ^ sw));
    // PV: acc[g][j] += P V  (B-operand from V^T rows = d)
    #pragma unroll
    for (int g=0; g<2; ++g)
      #pragma unroll
      for (int j=0; j<4; ++j){
        acc[g][j] = __builtin_amdgcn_mfma_f32_16x16x32_bf16(pa[g][0], vr[j][0], acc[g][j], 0,0,0);
        acc[g][j] = __builtin_amdgcn_mfma_f32_16x16x32_bf16(pa[g][1], vr[j][1], acc[g][j], 0,0,0);
      }
  }

  // epilogue: redistribute lrun to acc rows, scale, write ctx
  const int bb = bh >> 4, hh = bh & 15;
  #pragma unroll
  for (int g=0; g<2; ++g){
    float lr[4];
    #pragma unroll
    for (int r=0; r<4; ++r) lr[r] = __builtin_amdgcn_rcpf(__shfl(lrun[g], lg20 + r));
    #pragma unroll
    for (int j=0; j<4; ++j)
      #pragma unroll
      for (int r=0; r<4; ++r){
        int qg = q0w + 16*g + 4*lg + r;
        Ctx[(bb*SEQL + qg)*EMBED + hh*HDIM + 16*j + l15] = f2bf(acc[g][j][r] * lr[r]);
      }
  }
}

extern "C" void kernel_launch(void* const* d_in, const int* in_sizes, int n_in,
                              void* d_out, int out_size, void* d_ws, size_t ws_size,
                              hipStream_t stream){
  const float* x  = (const float*)d_in[0];
  const float* Wq = (const float*)d_in[1];
  const float* Wk = (const float*)d_in[2];
  const float* Wv = (const float*)d_in[3];
  const float* Wo = (const float*)d_in[4];
  const float* bo = (const float*)d_in[5];
  float* out = (float*)d_out;

  char* ws = (char*)d_ws;
  const size_t MB = 1u << 20;
  short* Xb  = (short*)(ws +  0*MB);  // [4096][1024] bf16 (8 MB)
  short* Wt  = (short*)(ws +  8*MB);  // 4x [1024][1024] bf16 transposed (8 MB)
  short* Q   = (short*)(ws + 16*MB);  // [b,h,s,d] (8 MB)
  short* Kk  = (short*)(ws + 24*MB);  // [b,h,s,d] (8 MB)
  short* Vt  = (short*)(ws + 32*MB);  // [b,h,d,s] (8 MB)
  short* Ctx = (short*)(ws + 40*MB);  // [b,s,e]   (8 MB)

  cvt_kernel<<<4096, 256, 0, stream>>>(x, Xb, MROWS*EMBED);
  transpose_kernel<<<dim3(32,32,4), 256, 0, stream>>>(Wq, Wk, Wv, Wo, Wt);
  gemm_qkv_kernel<<<dim3(32,8,3), 256, 0, stream>>>(Xb, Wt, Q, Kk, Vt);
  attn_kernel<<<1024, 128, 0, stream>>>(Q, Kk, Vt, Ctx);
  gemm_out_kernel<<<dim3(32,8), 256, 0, stream>>>(Ctx, Wt + 3*(EMBED*EMBED), bo, out);
}